// Round 4
// baseline (188.850 us; speedup 1.0000x reference)
//
#include <hip/hip_runtime.h>

#define TLEN     6000
#define NV4      1500        // float4 groups per series
#define CHUNK_V4 256         // float4 per chunk = 1024 elements
#define NCHUNK   6           // ceil(NV4 / CHUNK_V4)
#define V4PL     4           // main float4 per lane
#define EPT      16          // main elements per lane
#define WV4PL    2           // warm float4 per lane (512-element warm window)
#define EPS      1e-6f
#define LN_EPS   (-13.815511f) // ln(1e-6)
#define INV_EPS  1e6f

__device__ __forceinline__ float pcen_full(float xv, float M, float alpha,
                                           float delta, float r, float deltar) {
    float gain = __expf(-alpha * (LN_EPS + __logf(fmaf(M, INV_EPS, 1.0f))));
    return __powf(fmaf(xv, gain, delta), r) - deltar;
}

// b^e for integer e in [0,63] — exact, safe for b<=0, no cross-lane deps
__device__ __forceinline__ float ipow6(float b, int e) {
    float r = 1.0f;
    #pragma unroll
    for (int i = 0; i < 6; ++i) {
        if (e & 1) r *= b;
        b *= b;
        e >>= 1;
    }
    return r;
}

__global__ __launch_bounds__(256) void pcen_kernel(
    const float* __restrict__ x,
    const float* __restrict__ log_s,
    const float* __restrict__ log_alpha,
    const float* __restrict__ log_delta,
    const float* __restrict__ log_r,
    float* __restrict__ out,
    int num_series, int F)
{
    const int g    = (int)((blockIdx.x * blockDim.x + threadIdx.x) >> 6);
    const int lane = (int)(threadIdx.x & 63);
    if (g >= num_series * NCHUNK) return;
    const int series = g / NCHUNK;
    const int c      = g - series * NCHUNK;   // chunk index within series
    const int f      = series % F;

    const float4* __restrict__ xb = (const float4*)(x + (size_t)series * TLEN);
    float4* __restrict__ ob       = (float4*)(out + (size_t)series * TLEN);

    // ---- issue all fast-path loads first (6 independent float4 loads) ----
    const int tb = c * CHUNK_V4 + 4 * lane;                 // main base (float4)
    const int wb = c * CHUNK_V4 - 128 + WV4PL * lane;       // warm base (float4)
    float4 wq[WV4PL], q[V4PL];
    if (c > 0) {                                            // warm window always in-bounds
        #pragma unroll
        for (int j = 0; j < WV4PL; ++j) wq[j] = xb[wb + j];
    }
    #pragma unroll
    for (int j = 0; j < V4PL; ++j)
        q[j] = (tb + j < NV4) ? xb[tb + j] : make_float4(0.f, 0.f, 0.f, 0.f);

    const float la = log_alpha[f], ld = log_delta[f], lr = log_r[f];
    const bool  triv = (la == 0.0f) && (ld == 0.0f) && (lr == 0.0f);

    const float s   = __expf(log_s[f]);
    const float oms = 1.0f - s;

    // pw[k] = oms^k, k=0..16
    float pw[EPT + 1];
    pw[0] = 1.0f;
    #pragma unroll
    for (int k = 1; k <= EPT; ++k) pw[k] = pw[k - 1] * oms;
    const float oms8 = pw[8];
    const float omsP = pw[16];

    // warm-window total decay oms^512 = oms8^64 (6 squarings); truncation guard
    float Awarm = oms8;
    #pragma unroll
    for (int i = 0; i < 6; ++i) Awarm *= Awarm;
    const bool decay_ok = fabsf(Awarm) < 1e-5f;

    // general-path params
    const float alpha  = __expf(la);
    const float delta  = __expf(ld);
    const float r      = __expf(lr);
    const float deltar = __powf(delta, lr == 0.0f ? 1.0f : r);

    float Mc = 0.0f;   // smoother state entering the main chunk

    if (decay_ok) {
        // ---- warm 512 elements: per-lane 8-FMA chain + weighted xor-reduce ----
        if (c > 0) {
            float B = 0.0f;
            #pragma unroll
            for (int j = 0; j < WV4PL; ++j) {
                const float4 xq = wq[j];
                B = fmaf(oms, B, s * xq.x);
                B = fmaf(oms, B, s * xq.y);
                B = fmaf(oms, B, s * xq.z);
                B = fmaf(oms, B, s * xq.w);
            }
            float v = ipow6(oms8, 63 - lane) * B;   // decay from lane-segment end to window end
            #pragma unroll
            for (int off = 1; off < 64; off <<= 1)
                v += __shfl_xor(v, off, 64);
            Mc = v;   // truncated-start term < 1e-5 * M — guarded above
        }
    } else {
        // ---- exact fallback: accumulate ALL earlier chunks (rare path) ----
        float Achunk = omsP;                       // oms^1024 = omsP^64
        #pragma unroll
        for (int i = 0; i < 6; ++i) Achunk *= Achunk;
        const float wl16 = ipow6(omsP, 63 - lane);
        for (int wc = 0; wc < c; ++wc) {
            const int b0 = wc * CHUNK_V4 + 4 * lane;
            float B = 0.0f;
            #pragma unroll
            for (int j = 0; j < V4PL; ++j) {
                const float4 xq = xb[b0 + j];
                const float c0 = (wc == 0 && lane == 0 && j == 0) ? 1.0f : s;
                B = fmaf(oms, B, c0 * xq.x);
                B = fmaf(oms, B, s  * xq.y);
                B = fmaf(oms, B, s  * xq.z);
                B = fmaf(oms, B, s  * xq.w);
            }
            float v = wl16 * B;
            #pragma unroll
            for (int off = 1; off < 64; off <<= 1)
                v += __shfl_xor(v, off, 64);
            Mc = fmaf(Achunk, Mc, v);
        }
    }

    // ---- main chunk: per-lane 16-FMA chain with stored prefixes ----
    float Bv[EPT];
    float B = 0.0f;
    #pragma unroll
    for (int j = 0; j < V4PL; ++j) {
        if (tb + j < NV4) {
            const float4 xq = q[j];
            const float c0 = (c == 0 && lane == 0 && j == 0) ? 1.0f : s;
            B = fmaf(oms, B, c0 * xq.x); Bv[4 * j + 0] = B;
            B = fmaf(oms, B, s  * xq.y); Bv[4 * j + 1] = B;
            B = fmaf(oms, B, s  * xq.z); Bv[4 * j + 2] = B;
            B = fmaf(oms, B, s  * xq.w); Bv[4 * j + 3] = B;
        }
    }

    // ---- uniform-A inclusive B-scan: per-level wave-uniform multiplier omsP^off ----
    // (A-component is analytic: every valid lane's segment decay == omsP.
    //  Chunk-0 lane-0's A=0 exception is harmless: it only affects Aexc, and Mc==0 there.)
    {
        float cc = omsP;
        #pragma unroll
        for (int off = 1; off < 64; off <<= 1) {
            const float Bp = __shfl_up(B, off, 64);
            if (lane >= off) B = fmaf(cc, Bp, B);
            cc *= cc;
        }
    }
    float Be = __shfl_up(B, 1, 64);
    if (lane == 0) Be = 0.0f;
    const float Ae  = ipow6(omsP, lane);       // omsP^lane (off critical path)
    const float Min = fmaf(Ae, Mc, Be);        // smoother entering this lane's segment

    // ---- epilogue: M_t = oms^(t+1) * Min + Bv[t] ----
    if (triv) {
        // alpha=delta=r=1  =>  out = x / (eps + M)  (exact algebraic reduction)
        #pragma unroll
        for (int j = 0; j < V4PL; ++j) {
            if (tb + j < NV4) {
                const float4 xq = q[j];
                float4 o; float m;
                m = fmaf(pw[4 * j + 1], Min, Bv[4 * j + 0]);
                o.x = xq.x * __builtin_amdgcn_rcpf(m + EPS);
                m = fmaf(pw[4 * j + 2], Min, Bv[4 * j + 1]);
                o.y = xq.y * __builtin_amdgcn_rcpf(m + EPS);
                m = fmaf(pw[4 * j + 3], Min, Bv[4 * j + 2]);
                o.z = xq.z * __builtin_amdgcn_rcpf(m + EPS);
                m = fmaf(pw[4 * j + 4], Min, Bv[4 * j + 3]);
                o.w = xq.w * __builtin_amdgcn_rcpf(m + EPS);
                ob[tb + j] = o;
            }
        }
    } else {
        #pragma unroll
        for (int j = 0; j < V4PL; ++j) {
            if (tb + j < NV4) {
                const float4 xq = q[j];
                float4 o; float m;
                m = fmaf(pw[4 * j + 1], Min, Bv[4 * j + 0]);
                o.x = pcen_full(xq.x, m, alpha, delta, r, deltar);
                m = fmaf(pw[4 * j + 2], Min, Bv[4 * j + 1]);
                o.y = pcen_full(xq.y, m, alpha, delta, r, deltar);
                m = fmaf(pw[4 * j + 3], Min, Bv[4 * j + 2]);
                o.z = pcen_full(xq.z, m, alpha, delta, r, deltar);
                m = fmaf(pw[4 * j + 4], Min, Bv[4 * j + 3]);
                o.w = pcen_full(xq.w, m, alpha, delta, r, deltar);
                ob[tb + j] = o;
            }
        }
    }
}

extern "C" void kernel_launch(void* const* d_in, const int* in_sizes, int n_in,
                              void* d_out, int out_size, void* d_ws, size_t ws_size,
                              hipStream_t stream) {
    const float* x         = (const float*)d_in[0];
    const float* log_s     = (const float*)d_in[1];
    const float* log_alpha = (const float*)d_in[2];
    const float* log_delta = (const float*)d_in[3];
    const float* log_r     = (const float*)d_in[4];
    float* out             = (float*)d_out;

    const int F = in_sizes[1];                 // 128 bands
    const int num_series = in_sizes[0] / TLEN; // 4096
    const int num_waves  = num_series * NCHUNK;
    const int num_threads = num_waves * 64;
    const int grid = (num_threads + 255) / 256;

    pcen_kernel<<<grid, 256, 0, stream>>>(x, log_s, log_alpha, log_delta, log_r,
                                          out, num_series, F);
}